// Round 9
// baseline (53.125 us; speedup 1.0000x reference)
//
#include <hip/hip_runtime.h>

#define N_SAMPLES 128
#define NUM_OBJECTS 8
#define NUM_POINTS 100000
#define GROUPS 25000           // groups of 4 points (48 B / 12 floats each)
#define TPB 256
#define CHUNKS 64              // blocks per object; 64*256*2 groups = 32768 >= 25000
#define MAXS 128
#define NBLOCKS (CHUNKS * NUM_OBJECTS)   // 512 = 2 blocks/CU
#define COUNTER_IDX 8192       // float index in ws; used as unsigned ticket counter

// 4 packed points from 12 floats f[0..11]:
// p0=(f0,f1,f2) p1=(f3,f4,f5) p2=(f6,f7,f8) p3=(f9,f10,f11)
__device__ __forceinline__ float pts4_l1(
    const float* __restrict__ f,
    float d0, float d1, float d2, float d3, float d4,
    float d5, float d6, float d7, float d8)
{
    float s;
    s  = fabsf(d0 * f[0] + d1 * f[1]  + d2 * f[2])
       + fabsf(d3 * f[0] + d4 * f[1]  + d5 * f[2])
       + fabsf(d6 * f[0] + d7 * f[1]  + d8 * f[2]);
    s += fabsf(d0 * f[3] + d1 * f[4]  + d2 * f[5])
       + fabsf(d3 * f[3] + d4 * f[4]  + d5 * f[5])
       + fabsf(d6 * f[3] + d7 * f[4]  + d8 * f[5]);
    s += fabsf(d0 * f[6] + d1 * f[7]  + d2 * f[8])
       + fabsf(d3 * f[6] + d4 * f[7]  + d5 * f[8])
       + fabsf(d6 * f[6] + d7 * f[7]  + d8 * f[8]);
    s += fabsf(d0 * f[9] + d1 * f[10] + d2 * f[11])
       + fabsf(d3 * f[9] + d4 * f[10] + d5 * f[11])
       + fabsf(d6 * f[9] + d7 * f[10] + d8 * f[11]);
    return s;
}

// ONE dispatch. Phase 1: round-4 pm_partial (block b -> object b>>6, chunk
// b&63; unscaled partial per (sample, chunk) -> ws, plain stores). Then the
// threadfence-reduction protocol: every block fences + takes a ticket; the
// block holding ticket ≡ 511 (mod 512) — exactly one per replay, for ANY
// initial counter value (poison-proof) — subtracts 512 (self-healing) and
// computes all 384 outputs from the partials with agent-scope loads.
__global__ __launch_bounds__(TPB) void pm_onedispatch_kernel(
    const int* __restrict__ obj_id,
    const float* __restrict__ gtR, const float* __restrict__ prR,
    const float* __restrict__ gt_t, const float* __restrict__ pred_t,
    const float* __restrict__ pts, const float* __restrict__ diam,
    float* __restrict__ ws, float* __restrict__ out)
{
    const int o     = blockIdx.x >> 6;
    const int chunk = blockIdx.x & (CHUNKS - 1);
    const int tid   = threadIdx.x;

    __shared__ int   s_cnt;
    __shared__ int   s_last;
    __shared__ int   s_sidx[MAXS];
    __shared__ float s_dR[MAXS][12];      // rows padded to 12 for b128 reads
    __shared__ float s_part[8][MAXS];     // 8 half-wave partials per sample

    if (tid == 0) s_cnt = 0;
    __syncthreads();
    if (tid < N_SAMPLES) {
        const int n = tid;
        if (obj_id[n] == o) {
            int slot = atomicAdd(&s_cnt, 1);   // LDS atomic, one-time
            s_sidx[slot] = n;
            #pragma unroll
            for (int j = 0; j < 9; ++j)
                s_dR[slot][j] = prR[n * 9 + j] - gtR[n * 9 + j];
        }
    }
    __syncthreads();
    const int nsamp = s_cnt;
    const int nsamp_pad = (nsamp + 3) & ~3;
    {   // zero the <=3 pad rows
        const int idx = nsamp + tid;
        if (idx < nsamp_pad) {
            #pragma unroll
            for (int j = 0; j < 9; ++j) s_dR[idx][j] = 0.0f;
        }
    }
    __syncthreads();

    if (nsamp > 0) {   // all blocks (even empty ones) must reach the ticket
        const float4* __restrict__ p4 =
            (const float4*)(pts + (size_t)o * (size_t)NUM_POINTS * 3);
        const int g0 = chunk * TPB + tid;     // <= 16383 < GROUPS: always valid
        const int g1 = g0 + CHUNKS * TPB;     // may exceed GROUPS
        float4 a0 = p4[g0 * 3 + 0], b0 = p4[g0 * 3 + 1], c0 = p4[g0 * 3 + 2];
        const float valid = (g1 < GROUPS) ? 1.0f : 0.0f;
        const int g1c = min(g1, GROUPS - 1);
        float4 a1 = p4[g1c * 3 + 0], b1 = p4[g1c * 3 + 1], c1 = p4[g1c * 3 + 2];
        float f0[12] = { a0.x, a0.y, a0.z, a0.w, b0.x, b0.y,
                         b0.z, b0.w, c0.x, c0.y, c0.z, c0.w };
        float f1[12] = { a1.x * valid, a1.y * valid, a1.z * valid, a1.w * valid,
                         b1.x * valid, b1.y * valid, b1.z * valid, b1.w * valid,
                         c1.x * valid, c1.y * valid, c1.z * valid, c1.w * valid };

        const int lane = tid & 63;
        const int half = (tid >> 6) * 2 + ((lane >> 5) & 1);

        for (int s0 = 0; s0 < nsamp_pad; s0 += 4) {
            float acc[4];
            #pragma unroll
            for (int k = 0; k < 4; ++k) {
                float4 q0 = *(const float4*)&s_dR[s0 + k][0];
                float4 q1 = *(const float4*)&s_dR[s0 + k][4];
                float4 q2 = *(const float4*)&s_dR[s0 + k][8];
                acc[k] = pts4_l1(f0, q0.x, q0.y, q0.z, q0.w,
                                     q1.x, q1.y, q1.z, q1.w, q2.x)
                       + pts4_l1(f1, q0.x, q0.y, q0.z, q0.w,
                                     q1.x, q1.y, q1.z, q1.w, q2.x);
            }
            #pragma unroll
            for (int off = 1; off <= 16; off <<= 1) {
                #pragma unroll
                for (int k = 0; k < 4; ++k)
                    acc[k] += __shfl_xor(acc[k], off, 64);
            }
            if ((lane & 31) == 0) {
                #pragma unroll
                for (int k = 0; k < 4; ++k)
                    s_part[half][s0 + k] = acc[k];
            }
        }
        __syncthreads();

        if (tid < nsamp)
        {
            float v = 0.0f;
            #pragma unroll
            for (int w = 0; w < 8; ++w) v += s_part[w][tid];
            ws[(size_t)s_sidx[tid] * CHUNKS + chunk] = v;  // unscaled partial
        }
    }

    // ---- completion protocol (threadfence reduction) ----
    __threadfence();            // make this block's partials agent-visible
    __syncthreads();
    if (tid == 0) {
        unsigned t = atomicAdd((unsigned*)ws + COUNTER_IDX, 1u);
        s_last = ((t & (NBLOCKS - 1)) == (NBLOCKS - 1)) ? 1 : 0;
    }
    __syncthreads();
    if (!s_last) return;

    // finisher: self-heal the counter, then produce all outputs
    if (tid == 0)
        atomicAdd((unsigned*)ws + COUNTER_IDX, (unsigned)(0u - NBLOCKS));
    __threadfence();

    // pm: 2 threads per sample, agent-scope loads (bypass stale L1)
    {
        const int n = tid >> 1;
        const int h = tid & 1;
        const float* row = ws + (size_t)n * CHUNKS + h * 32;
        float v = 0.0f;
        #pragma unroll
        for (int i = 0; i < 32; ++i)
            v += __hip_atomic_load(row + i, __ATOMIC_RELAXED,
                                   __HIP_MEMORY_SCOPE_AGENT);
        v += __shfl_xor(v, 1, 64);
        if (h == 0)
            out[n] = v / ((float)NUM_POINTS * diam[obj_id[n]]);
    }
    // translation losses
    if (tid < N_SAMPLES) {
        const int n = tid;
        out[N_SAMPLES + n] = fabsf(gt_t[n * 3 + 0] - pred_t[n * 3 + 0])
                           + fabsf(gt_t[n * 3 + 1] - pred_t[n * 3 + 1]);
    } else {
        const int n = tid - N_SAMPLES;
        out[2 * N_SAMPLES + n] = fabsf(gt_t[n * 3 + 2] - pred_t[n * 3 + 2]);
    }
}

extern "C" void kernel_launch(void* const* d_in, const int* in_sizes, int n_in,
                              void* d_out, int out_size, void* d_ws, size_t ws_size,
                              hipStream_t stream) {
    const int*   obj_id = (const int*)d_in[0];
    const float* gtR    = (const float*)d_in[1];
    const float* prR    = (const float*)d_in[2];
    const float* gt_t   = (const float*)d_in[3];
    const float* pred_t = (const float*)d_in[4];
    const float* pts    = (const float*)d_in[5];
    const float* diam   = (const float*)d_in[6];
    float* out = (float*)d_out;
    float* ws  = (float*)d_ws;   // [0,8192): partials; [8192]: ticket counter

    pm_onedispatch_kernel<<<dim3(NBLOCKS), TPB, 0, stream>>>(
        obj_id, gtR, prR, gt_t, pred_t, pts, diam, ws, out);
}

// Round 10
// 17.807 us; speedup vs baseline: 2.9834x; 2.9834x over previous
//
#include <hip/hip_runtime.h>

#define N_SAMPLES 128
#define NUM_OBJECTS 8
#define NUM_POINTS 100000
#define GROUPS 25000           // groups of 4 points (48 B / 12 floats each)
#define TPB 256
#define CHUNKS 64              // 64 chunks * 256 thr * 2 groups = 32768 >= 25000
#define MAXS 128

// 4 packed points from 12 floats f[0..11]:
// p0=(f0,f1,f2) p1=(f3,f4,f5) p2=(f6,f7,f8) p3=(f9,f10,f11)
__device__ __forceinline__ float pts4_l1(
    const float* __restrict__ f,
    float d0, float d1, float d2, float d3, float d4,
    float d5, float d6, float d7, float d8)
{
    float s;
    s  = fabsf(d0 * f[0] + d1 * f[1]  + d2 * f[2])
       + fabsf(d3 * f[0] + d4 * f[1]  + d5 * f[2])
       + fabsf(d6 * f[0] + d7 * f[1]  + d8 * f[2]);
    s += fabsf(d0 * f[3] + d1 * f[4]  + d2 * f[5])
       + fabsf(d3 * f[3] + d4 * f[4]  + d5 * f[5])
       + fabsf(d6 * f[3] + d7 * f[4]  + d8 * f[5]);
    s += fabsf(d0 * f[6] + d1 * f[7]  + d2 * f[8])
       + fabsf(d3 * f[6] + d4 * f[7]  + d5 * f[8])
       + fabsf(d6 * f[6] + d7 * f[7]  + d8 * f[8]);
    s += fabsf(d0 * f[9] + d1 * f[10] + d2 * f[11])
       + fabsf(d3 * f[9] + d4 * f[10] + d5 * f[11])
       + fabsf(d6 * f[9] + d7 * f[10] + d8 * f[11]);
    return s;
}

// Kernel 1: grid = (CHUNKS, NUM_OBJECTS, 2). blockIdx.z picks half of the
// object's sample list (deterministic ballot ranks -> both half-blocks agree
// on the split). 1024 blocks = 4/CU for latency hiding. Point loads issued
// before the prologue so HBM latency overlaps it. Per (sample, chunk) one
// plain unscaled-partial store into ws; duplicates impossible, no atomics.
__global__ __launch_bounds__(TPB) void pm_partial_kernel(
    const int* __restrict__ obj_id,
    const float* __restrict__ gtR, const float* __restrict__ prR,
    const float* __restrict__ pts,
    float* __restrict__ ws)
{
    const int o    = blockIdx.y;
    const int hsel = blockIdx.z;
    const int tid  = threadIdx.x;

    // ---- issue point loads FIRST (no dependence on prologue) ----
    const float4* __restrict__ p4 =
        (const float4*)(pts + (size_t)o * (size_t)NUM_POINTS * 3);
    const int g0 = blockIdx.x * TPB + tid;     // < 16384 < GROUPS: valid
    const int g1 = g0 + CHUNKS * TPB;          // may exceed GROUPS
    const int g1c = min(g1, GROUPS - 1);
    float4 a0 = p4[g0 * 3 + 0], b0 = p4[g0 * 3 + 1], c0 = p4[g0 * 3 + 2];
    float4 a1 = p4[g1c * 3 + 0], b1 = p4[g1c * 3 + 1], c1 = p4[g1c * 3 + 2];
    const float valid = (g1 < GROUPS) ? 1.0f : 0.0f;

    // ---- deterministic ballot-rank prologue (no atomics) ----
    __shared__ int   s_wcnt[2];
    __shared__ int   s_sidx[MAXS];
    __shared__ float s_dR[MAXS + 4][12];   // +4: batch overrun rows (never stored)
    __shared__ float s_part[8][MAXS + 4];

    const int wave = tid >> 6;
    const int lane = tid & 63;
    const bool match = (tid < N_SAMPLES) && (obj_id[tid] == o);
    const unsigned long long mask = __ballot(match);
    if (wave < 2 && lane == 0) s_wcnt[wave] = __popcll(mask);
    __syncthreads();
    const int nsamp = s_wcnt[0] + s_wcnt[1];
    if (match) {
        const int rank = __popcll(mask & ((1ull << lane) - 1))
                       + (wave == 1 ? s_wcnt[0] : 0);
        s_sidx[rank] = tid;
        #pragma unroll
        for (int j = 0; j < 9; ++j)
            s_dR[rank][j] = prR[tid * 9 + j] - gtR[tid * 9 + j];
    }
    __syncthreads();

    // this block's half of the sample list (same split in both half-blocks)
    const int lo = (nsamp * hsel) >> 1;
    const int hi = (nsamp * (hsel + 1)) >> 1;

    float f0[12] = { a0.x, a0.y, a0.z, a0.w, b0.x, b0.y,
                     b0.z, b0.w, c0.x, c0.y, c0.z, c0.w };
    float f1[12] = { a1.x * valid, a1.y * valid, a1.z * valid, a1.w * valid,
                     b1.x * valid, b1.y * valid, b1.z * valid, b1.w * valid,
                     c1.x * valid, c1.y * valid, c1.z * valid, c1.w * valid };

    const int half = wave * 2 + ((lane >> 5) & 1);

    for (int s0 = lo; s0 < hi; s0 += 4) {      // batch overrun rows harmless
        float acc[4];
        #pragma unroll
        for (int k = 0; k < 4; ++k) {
            float4 q0 = *(const float4*)&s_dR[s0 + k][0];
            float4 q1 = *(const float4*)&s_dR[s0 + k][4];
            float4 q2 = *(const float4*)&s_dR[s0 + k][8];
            acc[k] = pts4_l1(f0, q0.x, q0.y, q0.z, q0.w,
                                 q1.x, q1.y, q1.z, q1.w, q2.x)
                   + pts4_l1(f1, q0.x, q0.y, q0.z, q0.w,
                                 q1.x, q1.y, q1.z, q1.w, q2.x);
        }
        #pragma unroll
        for (int off = 1; off <= 16; off <<= 1) {
            #pragma unroll
            for (int k = 0; k < 4; ++k)
                acc[k] += __shfl_xor(acc[k], off, 64);
        }
        if ((lane & 31) == 0) {
            #pragma unroll
            for (int k = 0; k < 4; ++k)
                s_part[half][s0 + k] = acc[k];
        }
    }
    __syncthreads();

    if (tid >= lo && tid < hi) {
        float v = 0.0f;
        #pragma unroll
        for (int w = 0; w < 8; ++w) v += s_part[w][tid];
        ws[(size_t)s_sidx[tid] * CHUNKS + blockIdx.x] = v;  // unscaled partial
    }
}

// Kernel 2: one wave per sample reduces the 64 chunk partials and scales;
// also emits the two translation losses. Every out element written once.
__global__ __launch_bounds__(64) void finish_kernel(
    const int* __restrict__ obj_id, const float* __restrict__ diam,
    const float* __restrict__ gt_t, const float* __restrict__ pred_t,
    const float* __restrict__ ws, float* __restrict__ out)
{
    const int n = blockIdx.x;
    const int t = threadIdx.x;
    float v = ws[(size_t)n * CHUNKS + t];   // CHUNKS == 64 == blockDim
    #pragma unroll
    for (int off = 1; off <= 32; off <<= 1)
        v += __shfl_xor(v, off, 64);
    if (t == 0) {
        out[n] = v / ((float)NUM_POINTS * diam[obj_id[n]]);
    } else if (t == 1) {
        out[N_SAMPLES + n] = fabsf(gt_t[n * 3 + 0] - pred_t[n * 3 + 0])
                           + fabsf(gt_t[n * 3 + 1] - pred_t[n * 3 + 1]);
    } else if (t == 2) {
        out[2 * N_SAMPLES + n] = fabsf(gt_t[n * 3 + 2] - pred_t[n * 3 + 2]);
    }
}

extern "C" void kernel_launch(void* const* d_in, const int* in_sizes, int n_in,
                              void* d_out, int out_size, void* d_ws, size_t ws_size,
                              hipStream_t stream) {
    const int*   obj_id = (const int*)d_in[0];
    const float* gtR    = (const float*)d_in[1];
    const float* prR    = (const float*)d_in[2];
    const float* gt_t   = (const float*)d_in[3];
    const float* pred_t = (const float*)d_in[4];
    const float* pts    = (const float*)d_in[5];
    const float* diam   = (const float*)d_in[6];
    float* out = (float*)d_out;
    float* ws  = (float*)d_ws;   // 128*64*4 B = 32 KB partials

    pm_partial_kernel<<<dim3(CHUNKS, NUM_OBJECTS, 2), TPB, 0, stream>>>(
        obj_id, gtR, prR, pts, ws);
    finish_kernel<<<N_SAMPLES, 64, 0, stream>>>(
        obj_id, diam, gt_t, pred_t, ws, out);
}